// Round 17
// baseline (304.347 us; speedup 1.0000x reference)
//
#include <hip/hip_runtime.h>

// MultiHeadAttention: B=2,S=2048,D=1024,H=16,Dh=64, fp32 in/out.
// All-bf16 single-term MFMA, swapped QK^T (sc = MFMA(K,Q)).
// K1: QKV projection, reg-prefetch pipeline. Q -> bf16 [4096][1024] pre-scaled
//     (1/8)*log2e; K -> bf16 [4096][1024]; V -> bf16 TRANSPOSED [1024][4096]
//     via LDS-transpose epilogue.
// K2 (R16 skeleton = 213us best, ONE change):
//     passA: 256-row K windows via gload_lds, dbuf (unchanged).
//     passB: K gload_lds 64-row dbuf, 1 barrier/tile; V now DIRECT L2->reg,
//            single 32-VGPR buffer loaded at TOP of each tile (consumed by PV
//            after QK+exp+store ~300-400cyc cover; R7: V panels are L2-hot,
//            FETCH 68MB; R8 lesson: dual reg buffers spill -> single only).
//            Removes V staging: -8 gload/tile-block, -64KB/tile LDS reads.
//            sP[128][128f] (264B stride); 512B-segment nt store phase.
//     NT stores throughout (R11-proven: keeps K/V L2-resident).
// ws: 8+8+8 = 24MB.

typedef __attribute__((ext_vector_type(8))) short bf16x8;
typedef __attribute__((ext_vector_type(4))) float f32x4;

#define MFMA16(a, b, c) __builtin_amdgcn_mfma_f32_16x16x32_bf16((a), (b), (c), 0, 0, 0)

static __device__ __forceinline__ unsigned short f2bf(float x) {
    __bf16 b = (__bf16)x;               // RNE; clang fuses pairs to v_cvt_pk_bf16_f32
    return __builtin_bit_cast(unsigned short, b);
}
static __device__ __forceinline__ float bf2f(unsigned short s) {
    return __builtin_bit_cast(float, ((unsigned int)s) << 16);
}

// async global(bf16,16B) -> LDS, dest = wave-uniform base + lane*16
static __device__ __forceinline__ void gload16(const unsigned short* g, unsigned short* l) {
    __builtin_amdgcn_global_load_lds(
        (const __attribute__((address_space(1))) unsigned int*)g,
        (__attribute__((address_space(3))) unsigned int*)l, 16, 0, 0);
}

// ---------------- K1: QKV projection GEMM  C[m,n] = sum_k X[m,k]*W[n,k] + b[n]
__global__ __launch_bounds__(256, 3) void qkv_proj(
    const float* __restrict__ query, const float* __restrict__ key_, const float* __restrict__ value,
    const float* __restrict__ Wq, const float* __restrict__ bq,
    const float* __restrict__ Wk, const float* __restrict__ bk,
    const float* __restrict__ Wv, const float* __restrict__ bv,
    unsigned short* __restrict__ qb_ws, unsigned short* __restrict__ kb_ws,
    unsigned short* __restrict__ vt_ws)
{
    // union: staging sA/sB (20480B) | V-transpose tile 128x132 ushorts
    __shared__ unsigned short smem1[16896];
    unsigned short* const sA = smem1;            // 128*40
    unsigned short* const sB = smem1 + 5120;     // 128*40
    unsigned short* const sT = smem1;            // 128 x 132 (V transpose)

    const int z = blockIdx.z;
    const float* __restrict__ X    = (z == 0) ? query : (z == 1) ? key_ : value;
    const float* __restrict__ W    = (z == 0) ? Wq    : (z == 1) ? Wk   : Wv;
    const float* __restrict__ bias = (z == 0) ? bq    : (z == 1) ? bk   : bv;

    const int t = threadIdx.x;
    const int l = t & 63;
    const int w = t >> 6;
    const int lr = l & 15;
    const int lk = (l >> 4) * 8;
    const int m0 = blockIdx.y * 128;
    const int n0 = blockIdx.x * 128;
    const int wr = (w >> 1) * 64;
    const int wc = (w & 1) * 64;
    const int srow = t >> 1;            // staging: 2 threads per 128-row, 16 floats each
    const int sc0 = (t & 1) * 16;

    f32x4 acc[4][4];
#pragma unroll
    for (int i = 0; i < 4; i++)
#pragma unroll
        for (int j = 0; j < 4; j++) acc[i][j] = (f32x4){0.f, 0.f, 0.f, 0.f};

    float4 fa[4], fb[4];
#pragma unroll
    for (int u = 0; u < 4; u++) {       // prologue: prefetch K-step 0
        fa[u] = *(const float4*)(&X[(size_t)(m0 + srow) * 1024 + sc0 + 4 * u]);
        fb[u] = *(const float4*)(&W[(size_t)(n0 + srow) * 1024 + sc0 + 4 * u]);
    }

    for (int kk = 0; kk < 1024; kk += 32) {
        __syncthreads();                // prev tile reads done
#pragma unroll
        for (int u = 0; u < 4; u++) {   // convert + LDS write from regs
            ushort4 ah, bh;
            ah.x = f2bf(fa[u].x); ah.y = f2bf(fa[u].y);
            ah.z = f2bf(fa[u].z); ah.w = f2bf(fa[u].w);
            bh.x = f2bf(fb[u].x); bh.y = f2bf(fb[u].y);
            bh.z = f2bf(fb[u].z); bh.w = f2bf(fb[u].w);
            const int si = srow * 40 + sc0 + 4 * u;
            *(ushort4*)(&sA[si]) = ah;
            *(ushort4*)(&sB[si]) = bh;
        }
        __syncthreads();                // writes visible
        if (kk + 32 < 1024) {
#pragma unroll
            for (int u = 0; u < 4; u++) {   // issue next loads: latency hides under MFMA
                fa[u] = *(const float4*)(&X[(size_t)(m0 + srow) * 1024 + kk + 32 + sc0 + 4 * u]);
                fb[u] = *(const float4*)(&W[(size_t)(n0 + srow) * 1024 + kk + 32 + sc0 + 4 * u]);
            }
        }
        bf16x8 Ah[4], Bh[4];
#pragma unroll
        for (int i = 0; i < 4; i++) {
            Ah[i] = *(const bf16x8*)(&sA[(wr + i * 16 + lr) * 40 + lk]);
            Bh[i] = *(const bf16x8*)(&sB[(wc + i * 16 + lr) * 40 + lk]);
        }
        __builtin_amdgcn_s_setprio(1);
#pragma unroll
        for (int i = 0; i < 4; i++)
#pragma unroll
            for (int j = 0; j < 4; j++)
                acc[i][j] = MFMA16(Ah[i], Bh[j], acc[i][j]);
        __builtin_amdgcn_s_setprio(0);
    }

    // epilogue: C/D layout col=lane&15, row=(lane>>4)*4+r
    if (z == 2) {
        // V: transpose via LDS -> coalesced 256B-segment stores to vt_ws[1024][4096]
        __syncthreads();                // all frag reads of sA/sB done; reuse as sT
#pragma unroll
        for (int i = 0; i < 4; i++)
#pragma unroll
            for (int j = 0; j < 4; j++) {
                const int gcol_l = wc + j * 16 + lr;
                const float bb = bias[n0 + gcol_l];
                ushort4 pk;
                pk.x = f2bf(acc[i][j][0] + bb);
                pk.y = f2bf(acc[i][j][1] + bb);
                pk.z = f2bf(acc[i][j][2] + bb);
                pk.w = f2bf(acc[i][j][3] + bb);
                *(ushort4*)(&sT[gcol_l * 132 + wr + i * 16 + (l >> 4) * 4]) = pk;
            }
        __syncthreads();
#pragma unroll
        for (int s2 = 0; s2 < 16; s2++) {       // 8 rows x 256B per step
            const int rowl = s2 * 8 + (t >> 5);
            const int coll = (t & 31) * 4;
            *(ushort4*)(&vt_ws[(size_t)(n0 + rowl) * 4096 + m0 + coll]) =
                *(const ushort4*)(&sT[rowl * 132 + coll]);
        }
    } else {
#pragma unroll
        for (int i = 0; i < 4; i++)
#pragma unroll
            for (int j = 0; j < 4; j++) {
                const int gcol = n0 + wc + j * 16 + lr;
                const float bb = bias[gcol];
                const int grow0 = m0 + wr + i * 16 + (l >> 4) * 4;
                if (z == 1) {  // K: bf16 row-major
#pragma unroll
                    for (int r = 0; r < 4; r++)
                        kb_ws[(size_t)(grow0 + r) * 1024 + gcol] = f2bf(acc[i][j][r] + bb);
                } else {       // Q: bf16, (1/sqrt(Dh))*log2e folded in (exp2 softmax)
#pragma unroll
                    for (int r = 0; r < 4; r++)
                        qb_ws[(size_t)(grow0 + r) * 1024 + gcol] =
                            f2bf((acc[i][j][r] + bb) * 0.1803368801111244f);
                }
            }
    }
}

// ---------------- K2 staging helpers (async, swizzled source; 8 waves)
// 64-row K tile: wave w stages rows [w*8, w*8+8)
static __device__ __forceinline__ void stageK64(
    const unsigned short* __restrict__ kb_ws, unsigned short* dst,
    int b, int h, int k0, int w, int l)
{
    const int row = w * 8 + (l >> 3);
    const int col = ((l & 7) * 8) ^ ((row & 7) << 3);
    gload16(&kb_ws[(size_t)(b * 2048 + k0 + row) * 1024 + h * 64 + col], &dst[w * 512]);
}
// pass A: stage a 256-row window; wave w owns rows [w*32, w*32+32)
static __device__ __forceinline__ void stageWin256(
    const unsigned short* __restrict__ kb_ws, unsigned short* dst,
    int b, int h, int k0, int w, int l)
{
#pragma unroll
    for (int u = 0; u < 4; u++) {
        const int row = w * 32 + u * 8 + (l >> 3);
        const int col = ((l & 7) * 8) ^ ((row & 7) << 3);
        gload16(&kb_ws[(size_t)(b * 2048 + k0 + row) * 1024 + h * 64 + col],
                &dst[w * 2048 + u * 512]);
    }
}

// V fragments of one 64-row tile, direct from global (L2-hit)
static __device__ __forceinline__ void loadVB(
    bf16x8 (&vb)[4][2], const unsigned short* __restrict__ vpan,
    int k0, int lr, int lg)
{
#pragma unroll
    for (int n = 0; n < 4; n++)
#pragma unroll
        for (int kc = 0; kc < 2; kc++)
            vb[n][kc] = *(const bf16x8*)(
                &vpan[(size_t)(n * 16 + lr) * 4096 + k0 + kc * 32 + lg * 8]);
}

// SWAPPED QK^T on one 64-row K tile (LDS), m=1: sc[n] holds P[k=n*16+lg*4+r][q=lr]
static __device__ __forceinline__ void scores64(
    const unsigned short* sK, const bf16x8 (&qf)[2],
    int lr, int lg, f32x4 (&sc)[4])
{
#pragma unroll
    for (int n = 0; n < 4; n++) sc[n] = (f32x4){0.f, 0.f, 0.f, 0.f};
    __builtin_amdgcn_s_setprio(1);
#pragma unroll
    for (int n = 0; n < 4; n++) {
        const int row = n * 16 + lr;
#pragma unroll
        for (int kc = 0; kc < 2; kc++) {
            const int idx = (row * 64 + kc * 32 + lg * 8) ^ ((row & 7) << 3);
            const bf16x8 kf = *(const bf16x8*)(&sK[idx]);
            sc[n] = MFMA16(kf, qf[kc], sc[n]);
        }
    }
    __builtin_amdgcn_s_setprio(0);
}

#define SP_STRIDE 264   // bytes per sP row: 128 floats as bf16 (256B) + 8B pad

// ---------------- K2: fused attention per (b, h, q-block of 128); 8 waves x 16q
__global__ __launch_bounds__(512, 4) void attn_fused(
    const unsigned short* __restrict__ qb_ws, const unsigned short* __restrict__ kb_ws,
    const unsigned short* __restrict__ vt_ws,
    float* __restrict__ ctx_out, float* __restrict__ attn_out)
{
    // 65KB (ushort idx):
    //   passA: kwin[2][256*64] at 0, 16384 (64KB)
    //   passB: sKA [0,4096) sKB [4096,8192); sP 128 rows x 264B from ushort 16384
    __shared__ unsigned short smem[33280];
    unsigned short* const kwin0 = smem;
    unsigned short* const kwin1 = smem + 16384;
    unsigned short* const sKA   = smem;
    unsigned short* const sKB   = smem + 4096;
    char* const sPb             = (char*)(smem + 16384);

    const int t = threadIdx.x;
    const int l = t & 63;
    const int w = t >> 6;               // 0..7
    const int lr = l & 15;
    const int lg = l >> 4;
    // XCD swizzle: 512 blocks = 8 XCDs x 64; chunk shares 4 (b,h) K/V panels (L2-fit)
    const int o  = (blockIdx.x & 7) * 64 + (blockIdx.x >> 3);
    const int qb = o & 15;
    const int h  = (o >> 4) & 15;
    const int b  = o >> 8;
    const int q0 = w * 16;              // this wave's 16 q-rows within the 128-block

    const unsigned short* __restrict__ vpan = vt_ws + (size_t)(h * 64) * 4096 + b * 2048;

    // Q fragments, bf16 direct (scale+log2e already folded by K1)
    bf16x8 qf[2];
    {
        const int grow = b * 2048 + qb * 128 + q0 + lr;
#pragma unroll
        for (int kc = 0; kc < 2; kc++)
            qf[kc] = *(const bf16x8*)(&qb_ws[(size_t)grow * 1024 + h * 64 + kc * 32 + lg * 8]);
    }

    // ---- pass A: lane-partial row sum of exp2(s); 256-row windows, dbuf
    float La = 0.f;                     // lane-local: q = q0 + lr

    stageWin256(kb_ws, kwin0, b, h, 0, w, l);
    __syncthreads();
    for (int kt = 0; kt < 8; kt++) {
        unsigned short* cur = (kt & 1) ? kwin1 : kwin0;
        unsigned short* nxt = (kt & 1) ? kwin0 : kwin1;
        if (kt < 7) stageWin256(kb_ws, nxt, b, h, (kt + 1) * 256, w, l);
#pragma unroll
        for (int sub = 0; sub < 4; sub++) {
            f32x4 sc[4];
            scores64(&cur[sub * 4096], qf, lr, lg, sc);
#pragma unroll
            for (int n = 0; n < 4; n++)
                La += (exp2f(sc[n][0]) + exp2f(sc[n][1])) +
                      (exp2f(sc[n][2]) + exp2f(sc[n][3]));
        }
        __syncthreads();                // drains prefetch; protects buffer reuse
    }

    float invL;
    {
        float v = La;                   // sum the 4 lg-copies of q = q0+lr
        v += __shfl_xor(v, 16);
        v += __shfl_xor(v, 32);
        invL = 1.0f / v;
    }
    float il4[4];                       // invL of q = q0 + lg*4 + i (ctx epilogue)
#pragma unroll
    for (int i = 0; i < 4; i++) il4[i] = __shfl(invL, lg * 4 + i);
    float ilA[8];                       // invL of q = q0 + 2i + (l>>5) (store phase)
#pragma unroll
    for (int i = 0; i < 8; i++) ilA[i] = __shfl(invL, 2 * i + (l >> 5));

    // ---- pass B: K gload_lds dbuf, V direct L2->reg (top-of-tile load),
    //      1 barrier/tile; 2-tile sP groups, 512B-segment nt stores
    f32x4 pv[4];
#pragma unroll
    for (int n = 0; n < 4; n++) pv[n] = (f32x4){0.f, 0.f, 0.f, 0.f};

    const size_t abase = (size_t)(h * 2 + b) * 2048 + qb * 128;

    stageK64(kb_ws, sKA, b, h, 0, w, l);
    __syncthreads();                    // K tile 0 staged
    for (int t2 = 0; t2 < 32; t2++) {
        const int cur = t2 & 1;
        unsigned short* const sKc = cur ? sKB : sKA;
        unsigned short* const sKn = cur ? sKA : sKB;
        if (t2 < 31) stageK64(kb_ws, sKn, b, h, (t2 + 1) * 64, w, l);

        // V for THIS tile: issue now, consume at PV after QK+exp(+store) cover
        bf16x8 vb[4][2];
        loadVB(vb, vpan, t2 * 64, lr, lg);

        f32x4 sc[4];
        scores64(sKc, qf, lr, lg, sc);

        // exp2 -> P' bf16x4 pairs into wave-private sP rows (b64), half=cur
        {
            char* const prow = sPb + (q0 + lr) * SP_STRIDE + cur * 128;
#pragma unroll
            for (int n = 0; n < 4; n++) {
                float4 e;
                e.x = exp2f(sc[n][0]);
                e.y = exp2f(sc[n][1]);
                e.z = exp2f(sc[n][2]);
                e.w = exp2f(sc[n][3]);
                uint2 pk;
                pk.x = (unsigned int)f2bf(e.x) | ((unsigned int)f2bf(e.y) << 16);
                pk.y = (unsigned int)f2bf(e.z) | ((unsigned int)f2bf(e.w) << 16);
                *(uint2*)(prow + n * 32 + lg * 8) = pk;
            }
        }
        // store phase after odd tile completes the 128-col group (512B segs, nt)
        if (cur) {
            const int g0 = (t2 >> 1) * 128;
            const int rsel = l >> 5;            // 0: lanes 0-31, 1: lanes 32-63
            const int lc = l & 31;
#pragma unroll
            for (int s = 0; s < 8; s++) {
                const int rq = q0 + 2 * s + rsel;
                ushort4 pk = *(const ushort4*)(sPb + rq * SP_STRIDE + lc * 8);
                const float il = ilA[s];
                f32x4 oo;
                oo[0] = bf2f(pk.x) * il;
                oo[1] = bf2f(pk.y) * il;
                oo[2] = bf2f(pk.z) * il;
                oo[3] = bf2f(pk.w) * il;
                __builtin_nontemporal_store(oo,
                    (f32x4*)(&attn_out[(abase + rq) * 2048 + g0 + lc * 4]));
            }
        }
        // PV: ctx += P' @ V over this 64-k tile (V in regs)
        __builtin_amdgcn_s_setprio(1);
#pragma unroll
        for (int kcl = 0; kcl < 2; kcl++) {
            const bf16x8 pa = *(const bf16x8*)(sPb + (q0 + lr) * SP_STRIDE + cur * 128 +
                                               kcl * 64 + lg * 16);
#pragma unroll
            for (int n = 0; n < 4; n++)
                pv[n] = MFMA16(pa, vb[n][kcl], pv[n]);
        }
        __builtin_amdgcn_s_setprio(0);
        __syncthreads();                // next K tile staged (issued one compute ago)
    }

    // epilogue: context = (P' @ V) / L ; pv: q = q0 + lg*4 + r, d = n*16 + lr
#pragma unroll
    for (int r = 0; r < 4; r++) {
        const int qloc = q0 + lg * 4 + r;
        const int sq = qb * 128 + qloc;
        const float il = il4[r];
#pragma unroll
        for (int n = 0; n < 4; n++)
            __builtin_nontemporal_store(pv[n][r] * il,
                &ctx_out[((size_t)(b * 2048 + sq)) * 1024 + h * 64 + n * 16 + lr]);
    }
}

extern "C" void kernel_launch(void* const* d_in, const int* in_sizes, int n_in,
                              void* d_out, int out_size, void* d_ws, size_t ws_size,
                              hipStream_t stream)
{
    const float* query = (const float*)d_in[0];
    const float* key_  = (const float*)d_in[1];
    const float* value = (const float*)d_in[2];
    const float* Wq = (const float*)d_in[3];
    const float* bq = (const float*)d_in[4];
    const float* Wk = (const float*)d_in[5];
    const float* bk = (const float*)d_in[6];
    const float* Wv = (const float*)d_in[7];
    const float* bv = (const float*)d_in[8];

    unsigned short* qb_ws = (unsigned short*)d_ws;                 // 8 MB bf16 (scaled)
    unsigned short* kb_ws = qb_ws + (size_t)4096 * 1024;           // 8 MB bf16
    unsigned short* vt_ws = kb_ws + (size_t)4096 * 1024;           // 8 MB bf16 V^T

    float* ctx_out  = (float*)d_out;
    float* attn_out = ctx_out + (size_t)2 * 2048 * 1024;

    dim3 g1(8, 32, 3);
    qkv_proj<<<g1, 256, 0, stream>>>(query, key_, value, Wq, bq, Wk, bk, Wv, bv,
                                     qb_ws, kb_ws, vt_ws);
    attn_fused<<<512, 512, 0, stream>>>(qb_ws, kb_ws, vt_ws, ctx_out, attn_out);
}

// Round 18
// 212.624 us; speedup vs baseline: 1.4314x; 1.4314x over previous
//
#include <hip/hip_runtime.h>

// MultiHeadAttention: B=2,S=2048,D=1024,H=16,Dh=64, fp32 in/out.
// All-bf16 single-term MFMA, swapped QK^T (sc = MFMA(K,Q)).
// K1: QKV projection, reg-prefetch pipeline. Q -> bf16 pre-scaled (1/8)*log2e;
//     K -> bf16 [4096][1024]; V -> bf16 TRANSPOSED [1024][4096] via LDS epilogue.
// K2 = R16 (213us best) + T4 COUNTED-VMCNT BARRIERS in pass B:
//     __syncthreads drained vmcnt(0) each tile (gloads AND 8 nt stores fully
//     retired = the m97 barrier-drain stall). Replaced with
//     s_waitcnt vmcnt(10) + raw s_barrier: only the PREVIOUS tile's 2 K/V
//     gloads must be retired (10 = 8 cur stores + 2 cur gloads allowed in
//     flight). Stores drain one tile later with full compute cover.
//     passA: 256-row K windows via gload_lds, dbuf (full barriers, unchanged).
//     passB: K+V gload_lds 64-row dbuf; sP[128][128f] 264B stride; 512B nt
//     store segments. NT stores throughout (R11).
// ws: 8+8+8 = 24MB.

typedef __attribute__((ext_vector_type(8))) short bf16x8;
typedef __attribute__((ext_vector_type(4))) float f32x4;

#define MFMA16(a, b, c) __builtin_amdgcn_mfma_f32_16x16x32_bf16((a), (b), (c), 0, 0, 0)

// T4 barrier: prev tile's K/V gloads retired; cur stores+gloads stay in flight
#define WAITBAR() do {                                          \
    asm volatile("s_waitcnt vmcnt(10)" ::: "memory");           \
    __builtin_amdgcn_s_barrier();                               \
    __builtin_amdgcn_sched_barrier(0);                          \
} while (0)

static __device__ __forceinline__ unsigned short f2bf(float x) {
    __bf16 b = (__bf16)x;               // RNE; clang fuses pairs to v_cvt_pk_bf16_f32
    return __builtin_bit_cast(unsigned short, b);
}
static __device__ __forceinline__ float bf2f(unsigned short s) {
    return __builtin_bit_cast(float, ((unsigned int)s) << 16);
}

// async global(bf16,16B) -> LDS, dest = wave-uniform base + lane*16
static __device__ __forceinline__ void gload16(const unsigned short* g, unsigned short* l) {
    __builtin_amdgcn_global_load_lds(
        (const __attribute__((address_space(1))) unsigned int*)g,
        (__attribute__((address_space(3))) unsigned int*)l, 16, 0, 0);
}

// ---------------- K1: QKV projection GEMM  C[m,n] = sum_k X[m,k]*W[n,k] + b[n]
__global__ __launch_bounds__(256, 3) void qkv_proj(
    const float* __restrict__ query, const float* __restrict__ key_, const float* __restrict__ value,
    const float* __restrict__ Wq, const float* __restrict__ bq,
    const float* __restrict__ Wk, const float* __restrict__ bk,
    const float* __restrict__ Wv, const float* __restrict__ bv,
    unsigned short* __restrict__ qb_ws, unsigned short* __restrict__ kb_ws,
    unsigned short* __restrict__ vt_ws)
{
    // union: staging sA/sB (20480B) | V-transpose tile 128x132 ushorts
    __shared__ unsigned short smem1[16896];
    unsigned short* const sA = smem1;            // 128*40
    unsigned short* const sB = smem1 + 5120;     // 128*40
    unsigned short* const sT = smem1;            // 128 x 132 (V transpose)

    const int z = blockIdx.z;
    const float* __restrict__ X    = (z == 0) ? query : (z == 1) ? key_ : value;
    const float* __restrict__ W    = (z == 0) ? Wq    : (z == 1) ? Wk   : Wv;
    const float* __restrict__ bias = (z == 0) ? bq    : (z == 1) ? bk   : bv;

    const int t = threadIdx.x;
    const int l = t & 63;
    const int w = t >> 6;
    const int lr = l & 15;
    const int lk = (l >> 4) * 8;
    const int m0 = blockIdx.y * 128;
    const int n0 = blockIdx.x * 128;
    const int wr = (w >> 1) * 64;
    const int wc = (w & 1) * 64;
    const int srow = t >> 1;            // staging: 2 threads per 128-row, 16 floats each
    const int sc0 = (t & 1) * 16;

    f32x4 acc[4][4];
#pragma unroll
    for (int i = 0; i < 4; i++)
#pragma unroll
        for (int j = 0; j < 4; j++) acc[i][j] = (f32x4){0.f, 0.f, 0.f, 0.f};

    float4 fa[4], fb[4];
#pragma unroll
    for (int u = 0; u < 4; u++) {       // prologue: prefetch K-step 0
        fa[u] = *(const float4*)(&X[(size_t)(m0 + srow) * 1024 + sc0 + 4 * u]);
        fb[u] = *(const float4*)(&W[(size_t)(n0 + srow) * 1024 + sc0 + 4 * u]);
    }

    for (int kk = 0; kk < 1024; kk += 32) {
        __syncthreads();                // prev tile reads done
#pragma unroll
        for (int u = 0; u < 4; u++) {   // convert + LDS write from regs
            ushort4 ah, bh;
            ah.x = f2bf(fa[u].x); ah.y = f2bf(fa[u].y);
            ah.z = f2bf(fa[u].z); ah.w = f2bf(fa[u].w);
            bh.x = f2bf(fb[u].x); bh.y = f2bf(fb[u].y);
            bh.z = f2bf(fb[u].z); bh.w = f2bf(fb[u].w);
            const int si = srow * 40 + sc0 + 4 * u;
            *(ushort4*)(&sA[si]) = ah;
            *(ushort4*)(&sB[si]) = bh;
        }
        __syncthreads();                // writes visible
        if (kk + 32 < 1024) {
#pragma unroll
            for (int u = 0; u < 4; u++) {   // issue next loads: latency hides under MFMA
                fa[u] = *(const float4*)(&X[(size_t)(m0 + srow) * 1024 + kk + 32 + sc0 + 4 * u]);
                fb[u] = *(const float4*)(&W[(size_t)(n0 + srow) * 1024 + kk + 32 + sc0 + 4 * u]);
            }
        }
        bf16x8 Ah[4], Bh[4];
#pragma unroll
        for (int i = 0; i < 4; i++) {
            Ah[i] = *(const bf16x8*)(&sA[(wr + i * 16 + lr) * 40 + lk]);
            Bh[i] = *(const bf16x8*)(&sB[(wc + i * 16 + lr) * 40 + lk]);
        }
        __builtin_amdgcn_s_setprio(1);
#pragma unroll
        for (int i = 0; i < 4; i++)
#pragma unroll
            for (int j = 0; j < 4; j++)
                acc[i][j] = MFMA16(Ah[i], Bh[j], acc[i][j]);
        __builtin_amdgcn_s_setprio(0);
    }

    // epilogue: C/D layout col=lane&15, row=(lane>>4)*4+r
    if (z == 2) {
        // V: transpose via LDS -> coalesced 256B-segment stores to vt_ws[1024][4096]
        __syncthreads();                // all frag reads of sA/sB done; reuse as sT
#pragma unroll
        for (int i = 0; i < 4; i++)
#pragma unroll
            for (int j = 0; j < 4; j++) {
                const int gcol_l = wc + j * 16 + lr;
                const float bb = bias[n0 + gcol_l];
                ushort4 pk;
                pk.x = f2bf(acc[i][j][0] + bb);
                pk.y = f2bf(acc[i][j][1] + bb);
                pk.z = f2bf(acc[i][j][2] + bb);
                pk.w = f2bf(acc[i][j][3] + bb);
                *(ushort4*)(&sT[gcol_l * 132 + wr + i * 16 + (l >> 4) * 4]) = pk;
            }
        __syncthreads();
#pragma unroll
        for (int s2 = 0; s2 < 16; s2++) {       // 8 rows x 256B per step
            const int rowl = s2 * 8 + (t >> 5);
            const int coll = (t & 31) * 4;
            *(ushort4*)(&vt_ws[(size_t)(n0 + rowl) * 4096 + m0 + coll]) =
                *(const ushort4*)(&sT[rowl * 132 + coll]);
        }
    } else {
#pragma unroll
        for (int i = 0; i < 4; i++)
#pragma unroll
            for (int j = 0; j < 4; j++) {
                const int gcol = n0 + wc + j * 16 + lr;
                const float bb = bias[gcol];
                const int grow0 = m0 + wr + i * 16 + (l >> 4) * 4;
                if (z == 1) {  // K: bf16 row-major
#pragma unroll
                    for (int r = 0; r < 4; r++)
                        kb_ws[(size_t)(grow0 + r) * 1024 + gcol] = f2bf(acc[i][j][r] + bb);
                } else {       // Q: bf16, (1/sqrt(Dh))*log2e folded in (exp2 softmax)
#pragma unroll
                    for (int r = 0; r < 4; r++)
                        qb_ws[(size_t)(grow0 + r) * 1024 + gcol] =
                            f2bf((acc[i][j][r] + bb) * 0.1803368801111244f);
                }
            }
    }
}

// ---------------- K2 staging helpers (async, swizzled source; 8 waves)
// 64-row K tile: wave w stages rows [w*8, w*8+8)  (ONE gload per wave)
static __device__ __forceinline__ void stageK64(
    const unsigned short* __restrict__ kb_ws, unsigned short* dst,
    int b, int h, int k0, int w, int l)
{
    const int row = w * 8 + (l >> 3);
    const int col = ((l & 7) * 8) ^ ((row & 7) << 3);
    gload16(&kb_ws[(size_t)(b * 2048 + k0 + row) * 1024 + h * 64 + col], &dst[w * 512]);
}
static __device__ __forceinline__ void stageV64(
    const unsigned short* __restrict__ vt_ws, unsigned short* dst,
    int b, int h, int k0, int w, int l)
{
    const int d = w * 8 + (l >> 3);
    const int kk = ((l & 7) * 8) ^ ((d & 7) << 3);
    gload16(&vt_ws[(size_t)(h * 64 + d) * 4096 + b * 2048 + k0 + kk], &dst[w * 512]);
}
// pass A: stage a 256-row window; wave w owns rows [w*32, w*32+32)
static __device__ __forceinline__ void stageWin256(
    const unsigned short* __restrict__ kb_ws, unsigned short* dst,
    int b, int h, int k0, int w, int l)
{
#pragma unroll
    for (int u = 0; u < 4; u++) {
        const int row = w * 32 + u * 8 + (l >> 3);
        const int col = ((l & 7) * 8) ^ ((row & 7) << 3);
        gload16(&kb_ws[(size_t)(b * 2048 + k0 + row) * 1024 + h * 64 + col],
                &dst[w * 2048 + u * 512]);
    }
}

// SWAPPED QK^T on one 64-row K tile (LDS), m=1: sc[n] holds P[k=n*16+lg*4+r][q=lr]
static __device__ __forceinline__ void scores64(
    const unsigned short* sK, const bf16x8 (&qf)[2],
    int lr, int lg, f32x4 (&sc)[4])
{
#pragma unroll
    for (int n = 0; n < 4; n++) sc[n] = (f32x4){0.f, 0.f, 0.f, 0.f};
    __builtin_amdgcn_s_setprio(1);
#pragma unroll
    for (int n = 0; n < 4; n++) {
        const int row = n * 16 + lr;
#pragma unroll
        for (int kc = 0; kc < 2; kc++) {
            const int idx = (row * 64 + kc * 32 + lg * 8) ^ ((row & 7) << 3);
            const bf16x8 kf = *(const bf16x8*)(&sK[idx]);
            sc[n] = MFMA16(kf, qf[kc], sc[n]);
        }
    }
    __builtin_amdgcn_s_setprio(0);
}

#define SP_STRIDE 264   // bytes per sP row: 128 floats as bf16 (256B) + 8B pad

// one pass-B tile: QK(LDS) -> exp -> P' into sP column half -> PV (no store)
static __device__ __forceinline__ void doTileQKP(
    const unsigned short* sK, const unsigned short* sV, const bf16x8 (&qf)[2],
    char* sPb, f32x4 (&pv)[4], int half, int q0, int lr, int lg)
{
    f32x4 sc[4];
    scores64(sK, qf, lr, lg, sc);

    // exp2 -> P' bf16x4 pairs into wave-private sP rows (b64)
    {
        char* const prow = sPb + (q0 + lr) * SP_STRIDE + half * 128;
#pragma unroll
        for (int n = 0; n < 4; n++) {
            float4 e;
            e.x = exp2f(sc[n][0]);
            e.y = exp2f(sc[n][1]);
            e.z = exp2f(sc[n][2]);
            e.w = exp2f(sc[n][3]);
            uint2 pk;
            pk.x = (unsigned int)f2bf(e.x) | ((unsigned int)f2bf(e.y) << 16);
            pk.y = (unsigned int)f2bf(e.z) | ((unsigned int)f2bf(e.w) << 16);
            *(uint2*)(prow + n * 32 + lg * 8) = pk;
        }
    }
    // PV: ctx += P' @ V over this 64-k tile (V from LDS, XOR-swizzled rows)
    __builtin_amdgcn_s_setprio(1);
#pragma unroll
    for (int kcl = 0; kcl < 2; kcl++) {
        const bf16x8 pa = *(const bf16x8*)(sPb + (q0 + lr) * SP_STRIDE + half * 128 +
                                           kcl * 64 + lg * 16);
#pragma unroll
        for (int n = 0; n < 4; n++) {
            const int vrow = n * 16 + lr;
            const bf16x8 vb = *(const bf16x8*)(
                &sV[(vrow * 64 + kcl * 32 + lg * 8) ^ ((vrow & 7) << 3)]);
            pv[n] = MFMA16(pa, vb, pv[n]);
        }
    }
    __builtin_amdgcn_s_setprio(0);
}

// ---------------- K2: fused attention per (b, h, q-block of 128); 8 waves x 16q
__global__ __launch_bounds__(512, 4) void attn_fused(
    const unsigned short* __restrict__ qb_ws, const unsigned short* __restrict__ kb_ws,
    const unsigned short* __restrict__ vt_ws,
    float* __restrict__ ctx_out, float* __restrict__ attn_out)
{
    // 65KB (ushort idx):
    //   passA: kwin[2][256*64] at 0, 16384 (64KB)
    //   passB: sKA [0,4096) sKB [4096,8192) sVA [8192,12288) sVB [12288,16384)
    //          sP 128 rows x 264B from ushort 16384 (33792B)
    __shared__ unsigned short smem[33280];
    unsigned short* const kwin0 = smem;
    unsigned short* const kwin1 = smem + 16384;
    unsigned short* const sKA   = smem;
    unsigned short* const sKB   = smem + 4096;
    unsigned short* const sVA   = smem + 8192;
    unsigned short* const sVB   = smem + 12288;
    char* const sPb             = (char*)(smem + 16384);

    const int t = threadIdx.x;
    const int l = t & 63;
    const int w = t >> 6;               // 0..7
    const int lr = l & 15;
    const int lg = l >> 4;
    // XCD swizzle: 512 blocks = 8 XCDs x 64; chunk shares 4 (b,h) K/V panels (L2-fit)
    const int o  = (blockIdx.x & 7) * 64 + (blockIdx.x >> 3);
    const int qb = o & 15;
    const int h  = (o >> 4) & 15;
    const int b  = o >> 8;
    const int q0 = w * 16;              // this wave's 16 q-rows within the 128-block

    // Q fragments, bf16 direct (scale+log2e already folded by K1)
    bf16x8 qf[2];
    {
        const int grow = b * 2048 + qb * 128 + q0 + lr;
#pragma unroll
        for (int kc = 0; kc < 2; kc++)
            qf[kc] = *(const bf16x8*)(&qb_ws[(size_t)grow * 1024 + h * 64 + kc * 32 + lg * 8]);
    }

    // ---- pass A: lane-partial row sum of exp2(s); 256-row windows, dbuf
    float La = 0.f;                     // lane-local: q = q0 + lr

    stageWin256(kb_ws, kwin0, b, h, 0, w, l);
    __syncthreads();
    for (int kt = 0; kt < 8; kt++) {
        unsigned short* cur = (kt & 1) ? kwin1 : kwin0;
        unsigned short* nxt = (kt & 1) ? kwin0 : kwin1;
        if (kt < 7) stageWin256(kb_ws, nxt, b, h, (kt + 1) * 256, w, l);
#pragma unroll
        for (int sub = 0; sub < 4; sub++) {
            f32x4 sc[4];
            scores64(&cur[sub * 4096], qf, lr, lg, sc);
#pragma unroll
            for (int n = 0; n < 4; n++)
                La += (exp2f(sc[n][0]) + exp2f(sc[n][1])) +
                      (exp2f(sc[n][2]) + exp2f(sc[n][3]));
        }
        __syncthreads();                // drains prefetch; protects buffer reuse
    }

    float invL;
    {
        float v = La;                   // sum the 4 lg-copies of q = q0+lr
        v += __shfl_xor(v, 16);
        v += __shfl_xor(v, 32);
        invL = 1.0f / v;
    }
    float il4[4];                       // invL of q = q0 + lg*4 + i (ctx epilogue)
#pragma unroll
    for (int i = 0; i < 4; i++) il4[i] = __shfl(invL, lg * 4 + i);
    float ilA[8];                       // invL of q = q0 + 2i + (l>>5) (store phase)
#pragma unroll
    for (int i = 0; i < 8; i++) ilA[i] = __shfl(invL, 2 * i + (l >> 5));

    // ---- pass B: K+V gload_lds dbuf; T4 counted-vmcnt barriers (vmcnt(10))
    f32x4 pv[4];
#pragma unroll
    for (int n = 0; n < 4; n++) pv[n] = (f32x4){0.f, 0.f, 0.f, 0.f};

    const size_t abase = (size_t)(h * 2 + b) * 2048 + qb * 128;

    stageK64(kb_ws, sKA, b, h, 0, w, l);
    stageV64(vt_ws, sVA, b, h, 0, w, l);
    __syncthreads();                    // prologue: tile 0 fully staged (full drain)
    for (int i = 0; i < 16; i++) {      // group i = tiles 2i, 2i+1; k-cols [i*128, i*128+128)
        const int t0 = i * 2;
        // even tile: compute A (P' -> half 0), prefetch t0+1 into B
        stageK64(kb_ws, sKB, b, h, (t0 + 1) * 64, w, l);
        stageV64(vt_ws, sVB, b, h, (t0 + 1) * 64, w, l);
        doTileQKP(sKA, sVA, qf, sPb, pv, 0, q0, lr, lg);
        WAITBAR();                      // prev gloads retired; cur 2 stay in flight
        // odd tile: compute B (P' -> half 1), prefetch t0+2 into A
        if (i < 15) {
            stageK64(kb_ws, sKA, b, h, (t0 + 2) * 64, w, l);
            stageV64(vt_ws, sVA, b, h, (t0 + 2) * 64, w, l);
        }
        doTileQKP(sKB, sVB, qf, sPb, pv, 1, q0, lr, lg);
        // store phase: 8 insts/wave, each = 2 rows x 512B contiguous (nt)
        {
            const int g0 = i * 128;
            const int rsel = l >> 5;            // 0: lanes 0-31, 1: lanes 32-63
            const int lc = l & 31;
#pragma unroll
            for (int s = 0; s < 8; s++) {
                const int rq = q0 + 2 * s + rsel;
                ushort4 pk = *(const ushort4*)(sPb + rq * SP_STRIDE + lc * 8);
                const float il = ilA[s];
                f32x4 oo;
                oo[0] = bf2f(pk.x) * il;
                oo[1] = bf2f(pk.y) * il;
                oo[2] = bf2f(pk.z) * il;
                oo[3] = bf2f(pk.w) * il;
                __builtin_nontemporal_store(oo,
                    (f32x4*)(&attn_out[(abase + rq) * 2048 + g0 + lc * 4]));
            }
        }
        WAITBAR();                      // stores + cur gloads stay outstanding
    }

    // epilogue: context = (P' @ V) / L ; pv: q = q0 + lg*4 + r, d = n*16 + lr
#pragma unroll
    for (int r = 0; r < 4; r++) {
        const int qloc = q0 + lg * 4 + r;
        const int sq = qb * 128 + qloc;
        const float il = il4[r];
#pragma unroll
        for (int n = 0; n < 4; n++)
            __builtin_nontemporal_store(pv[n][r] * il,
                &ctx_out[((size_t)(b * 2048 + sq)) * 1024 + h * 64 + n * 16 + lr]);
    }
}

extern "C" void kernel_launch(void* const* d_in, const int* in_sizes, int n_in,
                              void* d_out, int out_size, void* d_ws, size_t ws_size,
                              hipStream_t stream)
{
    const float* query = (const float*)d_in[0];
    const float* key_  = (const float*)d_in[1];
    const float* value = (const float*)d_in[2];
    const float* Wq = (const float*)d_in[3];
    const float* bq = (const float*)d_in[4];
    const float* Wk = (const float*)d_in[5];
    const float* bk = (const float*)d_in[6];
    const float* Wv = (const float*)d_in[7];
    const float* bv = (const float*)d_in[8];

    unsigned short* qb_ws = (unsigned short*)d_ws;                 // 8 MB bf16 (scaled)
    unsigned short* kb_ws = qb_ws + (size_t)4096 * 1024;           // 8 MB bf16
    unsigned short* vt_ws = kb_ws + (size_t)4096 * 1024;           // 8 MB bf16 V^T

    float* ctx_out  = (float*)d_out;
    float* attn_out = ctx_out + (size_t)2 * 2048 * 1024;

    dim3 g1(8, 32, 3);
    qkv_proj<<<g1, 256, 0, stream>>>(query, key_, value, Wq, bq, Wk, bk, Wv, bv,
                                     qb_ws, kb_ws, vt_ws);
    attn_fused<<<512, 512, 0, stream>>>(qb_ws, kb_ws, vt_ws, ctx_out, attn_out);
}